// Round 1
// baseline (1581.958 us; speedup 1.0000x reference)
//
#include <hip/hip_runtime.h>
#include <math.h>

// Problem constants (setup_inputs): B=2, N=2048, C=1024, H=16, d=64
constexpr int Bc = 2;
constexpr int Nc = 2048;
constexpr int Cc = 1024;
constexpr int Hc = 16;
constexpr int Dc = 64;

// ---------------------------------------------------------------------------
// RoPE tables: cos/sin (N x 32), computed in fp64 for fidelity to reference
// ---------------------------------------------------------------------------
__global__ void rope_tables(float* __restrict__ cosT, float* __restrict__ sinT) {
    int idx = blockIdx.x * blockDim.x + threadIdx.x;   // N*32 = 65536
    if (idx >= Nc * 32) return;
    int n = idx >> 5;
    int j = idx & 31;
    double inv = pow(10000.0, -(double)j / 32.0);
    double ang = (double)n * inv;
    cosT[idx] = (float)cos(ang);
    sinT[idx] = (float)sin(ang);
}

// ---------------------------------------------------------------------------
// In-place RoPE on q and k inside the qkv buffer
// qkv layout: [B][N][3][H][D] row-major (row stride 3*C = 3072)
// ---------------------------------------------------------------------------
__global__ void rope_apply(float* __restrict__ qkv,
                           const float* __restrict__ cosT,
                           const float* __restrict__ sinT) {
    int idx = blockIdx.x * blockDim.x + threadIdx.x;   // B*N*H*32 = 2^21
    int j = idx & 31;
    int h = (idx >> 5) & (Hc - 1);
    int n = (idx >> 9) & (Nc - 1);
    int b = idx >> 20;
    if (b >= Bc) return;

    float c = cosT[n * 32 + j];
    float s = sinT[n * 32 + j];
    size_t rowbase = ((size_t)(b * Nc + n)) * (3 * Cc) + h * Dc;

    float* qp = qkv + rowbase;             // q slice
    float x1 = qp[j], x2 = qp[j + 32];
    qp[j]      = x1 * c - x2 * s;
    qp[j + 32] = x1 * s + x2 * c;

    float* kp = qkv + rowbase + Cc;        // k slice
    x1 = kp[j]; x2 = kp[j + 32];
    kp[j]      = x1 * c - x2 * s;
    kp[j + 32] = x1 * s + x2 * c;
}

// ---------------------------------------------------------------------------
// fp32 tiled GEMM: C = A(MxK) @ B(KxN) [+ bias], all row-major.
// 128x128 tile, BK=16, 256 threads, 8x8 micro-tile per thread.
// M%128==0, N%128==0, K%16==0 required (holds for 4096x3072x1024 / 4096x1024x1024).
// ---------------------------------------------------------------------------
constexpr int BM = 128, BN = 128, BK = 16;

__global__ __launch_bounds__(256) void gemm128(
    const float* __restrict__ A, const float* __restrict__ Bm,
    const float* __restrict__ bias, float* __restrict__ C,
    int M, int N, int K) {
    __shared__ float As[BK][BM + 4];   // +4 pad keeps rows 16B-aligned (132*4=528B)
    __shared__ float Bs[BK][BN + 4];

    const int tid = threadIdx.x;
    const int tx = tid & 15;           // col group: cols tx*8 .. tx*8+7
    const int ty = tid >> 4;           // row group: rows ty*8 .. ty*8+7
    const int row0 = blockIdx.y * BM;
    const int col0 = blockIdx.x * BN;

    // staging-load indices
    const int ar = tid >> 2;           // 0..63   (A rows, +64 for second half)
    const int ac = (tid & 3) * 4;      // 0,4,8,12
    const int br = tid >> 4;           // 0..15   (B rows)
    const int bc = (tid & 15) * 8;     // 0..120

    float acc[8][8] = {};

    for (int k0 = 0; k0 < K; k0 += BK) {
        float4 a0 = *(const float4*)&A[(size_t)(row0 + ar) * K + k0 + ac];
        float4 a1 = *(const float4*)&A[(size_t)(row0 + ar + 64) * K + k0 + ac];
        float4 b0 = *(const float4*)&Bm[(size_t)(k0 + br) * N + col0 + bc];
        float4 b1 = *(const float4*)&Bm[(size_t)(k0 + br) * N + col0 + bc + 4];

        __syncthreads();               // previous tile fully consumed
        As[ac + 0][ar] = a0.x; As[ac + 1][ar] = a0.y;
        As[ac + 2][ar] = a0.z; As[ac + 3][ar] = a0.w;
        As[ac + 0][ar + 64] = a1.x; As[ac + 1][ar + 64] = a1.y;
        As[ac + 2][ar + 64] = a1.z; As[ac + 3][ar + 64] = a1.w;
        *(float4*)&Bs[br][bc]     = b0;
        *(float4*)&Bs[br][bc + 4] = b1;
        __syncthreads();

        #pragma unroll
        for (int k = 0; k < BK; ++k) {
            float av[8], bv[8];
            *(float4*)&av[0] = *(const float4*)&As[k][ty * 8];
            *(float4*)&av[4] = *(const float4*)&As[k][ty * 8 + 4];
            *(float4*)&bv[0] = *(const float4*)&Bs[k][tx * 8];
            *(float4*)&bv[4] = *(const float4*)&Bs[k][tx * 8 + 4];
            #pragma unroll
            for (int i = 0; i < 8; ++i)
                #pragma unroll
                for (int j = 0; j < 8; ++j)
                    acc[i][j] = fmaf(av[i], bv[j], acc[i][j]);
        }
    }

    // epilogue
    #pragma unroll
    for (int i = 0; i < 8; ++i) {
        int r = row0 + ty * 8 + i;
        #pragma unroll
        for (int j = 0; j < 8; j += 4) {
            int c = col0 + tx * 8 + j;
            float4 v = make_float4(acc[i][j], acc[i][j + 1],
                                   acc[i][j + 2], acc[i][j + 3]);
            if (bias) {
                v.x += bias[c];     v.y += bias[c + 1];
                v.z += bias[c + 2]; v.w += bias[c + 3];
            }
            *(float4*)&C[(size_t)r * N + c] = v;
        }
    }
}

// ---------------------------------------------------------------------------
// Flash attention, fp32, non-causal. One q-row per thread (q, o in registers),
// K/V tiles of 64 rows in LDS (broadcast reads). Online softmax.
// out layout: [B][N][H*D] (ready for the projection GEMM).
// ---------------------------------------------------------------------------
constexpr int KT = 64;

__global__ __launch_bounds__(256) void flash_attn(
    const float* __restrict__ qkv, float* __restrict__ out) {
    const int bh = blockIdx.y;
    const int b = bh / Hc;
    const int h = bh % Hc;
    const int qrow = blockIdx.x * blockDim.x + threadIdx.x;  // 0..N-1
    const int C3 = 3 * Cc;                                   // 3072
    const size_t base = (size_t)b * Nc * C3;

    float4 qreg[Dc / 4];
    {
        const float* qp = qkv + base + (size_t)qrow * C3 + h * Dc;
        #pragma unroll
        for (int i = 0; i < Dc / 4; ++i) qreg[i] = ((const float4*)qp)[i];
    }
    float4 o[Dc / 4];
    #pragma unroll
    for (int i = 0; i < Dc / 4; ++i) o[i] = make_float4(0.f, 0.f, 0.f, 0.f);
    float m = -1e30f, l = 0.f;

    __shared__ float4 Ks[KT * (Dc / 4)];   // 16 KB
    __shared__ float4 Vs[KT * (Dc / 4)];   // 16 KB
    const float scale = 0.125f;            // 1/sqrt(64)

    for (int k0 = 0; k0 < Nc; k0 += KT) {
        __syncthreads();
        // cooperative tile load: KT*D floats = 1024 float4 each for K and V
        #pragma unroll
        for (int i = 0; i < 4; ++i) {
            int idx = threadIdx.x + i * 256;     // 0..1023
            int r = idx >> 4;
            int c = idx & 15;
            const float* kp = qkv + base + (size_t)(k0 + r) * C3 + Cc + h * Dc;
            Ks[r * 16 + c] = ((const float4*)kp)[c];
            Vs[r * 16 + c] = ((const float4*)(kp + Cc))[c];
        }
        __syncthreads();

        #pragma unroll 2
        for (int kk = 0; kk < KT; ++kk) {
            float4 s4 = make_float4(0.f, 0.f, 0.f, 0.f);
            #pragma unroll
            for (int i = 0; i < Dc / 4; ++i) {
                float4 kv = Ks[kk * 16 + i];
                s4.x = fmaf(qreg[i].x, kv.x, s4.x);
                s4.y = fmaf(qreg[i].y, kv.y, s4.y);
                s4.z = fmaf(qreg[i].z, kv.z, s4.z);
                s4.w = fmaf(qreg[i].w, kv.w, s4.w);
            }
            float s = (s4.x + s4.y + s4.z + s4.w) * scale;
            float mnew = fmaxf(m, s);
            float corr = __expf(m - mnew);
            float p = __expf(s - mnew);
            l = l * corr + p;
            m = mnew;
            #pragma unroll
            for (int i = 0; i < Dc / 4; ++i) {
                float4 vv = Vs[kk * 16 + i];
                o[i].x = fmaf(o[i].x, corr, p * vv.x);
                o[i].y = fmaf(o[i].y, corr, p * vv.y);
                o[i].z = fmaf(o[i].z, corr, p * vv.z);
                o[i].w = fmaf(o[i].w, corr, p * vv.w);
            }
        }
    }

    float inv_l = 1.f / l;
    float* op = out + ((size_t)(b * Nc + qrow)) * Cc + h * Dc;
    #pragma unroll
    for (int i = 0; i < Dc / 4; ++i) {
        float4 v = o[i];
        v.x *= inv_l; v.y *= inv_l; v.z *= inv_l; v.w *= inv_l;
        ((float4*)op)[i] = v;
    }
}

// ---------------------------------------------------------------------------
extern "C" void kernel_launch(void* const* d_in, const int* in_sizes, int n_in,
                              void* d_out, int out_size, void* d_ws, size_t ws_size,
                              hipStream_t stream) {
    const float* x      = (const float*)d_in[0];   // (2,2048,1024)
    const float* w_qkv  = (const float*)d_in[1];   // (1024,3072)
    const float* w_proj = (const float*)d_in[2];   // (1024,1024)
    const float* b_proj = (const float*)d_in[3];   // (1024,)
    float* out = (float*)d_out;                    // (2,2048,1024)

    float* ws = (float*)d_ws;
    float* qkv     = ws;                               // 4096*3072 = 12,582,912 floats
    float* attnout = ws + (size_t)4096 * 3072;         // 4096*1024 =  4,194,304 floats
    float* cosT    = attnout + (size_t)4096 * 1024;    // 65,536 floats
    float* sinT    = cosT + Nc * 32;                   // 65,536 floats

    // 1. RoPE tables
    rope_tables<<<(Nc * 32 + 255) / 256, 256, 0, stream>>>(cosT, sinT);

    // 2. qkv = x @ w_qkv   (4096 x 3072 x 1024)
    gemm128<<<dim3(3072 / BN, 4096 / BM), 256, 0, stream>>>(
        x, w_qkv, nullptr, qkv, 4096, 3072, 1024);

    // 3. RoPE on q,k in place
    rope_apply<<<(Bc * Nc * Hc * 32) / 256, 256, 0, stream>>>(qkv, cosT, sinT);

    // 4. attention -> attnout [B][N][C]
    flash_attn<<<dim3(Nc / 256, Bc * Hc), 256, 0, stream>>>(qkv, attnout);

    // 5. out = attnout @ w_proj + b_proj   (4096 x 1024 x 1024)
    gemm128<<<dim3(1024 / BN, 4096 / BM), 256, 0, stream>>>(
        attnout, w_proj, b_proj, out, 4096, 1024, 1024);
}